// Round 1
// baseline (664.783 us; speedup 1.0000x reference)
//
#include <hip/hip_runtime.h>
#include <hip/hip_bf16.h>

#define T_TOK 512
#define H_DIM 2048
#define E_NUM 8
#define I_DIM 1024

// ---------------- workspace layout (bytes from d_ws) ----------------
// count  : int[8]
// bucket : int[8*512]           (pair ids, grouped by expert)
// pair_w : float[1024]          (combine weight per pair; pair = 2*t + k)
// act    : float[1024*1024]     (silu(gate)*up per pair)
// y      : float[1024*2048]     (per-pair expert output)
// total ~ 12.6 MB

// ---------------------------------------------------------------
// Kernel 1: routing. softmax over E=8 logits, top-2 (stable, lower
// index wins ties like lax.top_k), renormalize, bucket by expert.
// Single block, 512 threads = 512 tokens.
// ---------------------------------------------------------------
__global__ __launch_bounds__(512) void routing_kernel(
    const float* __restrict__ logits,
    int* __restrict__ count, int* __restrict__ bucket,
    float* __restrict__ pair_w)
{
    int t = threadIdx.x;
    if (t < E_NUM) count[t] = 0;
    __syncthreads();

    float l[E_NUM];
    float m = -INFINITY;
#pragma unroll
    for (int e = 0; e < E_NUM; ++e) {
        l[e] = logits[t * E_NUM + e];
        m = fmaxf(m, l[e]);
    }
    float p[E_NUM];
    float s = 0.f;
#pragma unroll
    for (int e = 0; e < E_NUM; ++e) { p[e] = expf(l[e] - m); s += p[e]; }
    // probs = p/s; top-2 of probs == top-2 of p (monotonic)
    int i0 = 0;
#pragma unroll
    for (int e = 1; e < E_NUM; ++e) if (p[e] > p[i0]) i0 = e;
    int i1 = (i0 == 0) ? 1 : 0;
#pragma unroll
    for (int e = 0; e < E_NUM; ++e) {
        if (e != i0 && p[e] > p[i1]) i1 = e;
    }
    float denom = p[i0] + p[i1];
    float w0 = p[i0] / denom;
    float w1 = p[i1] / denom;

    pair_w[2 * t + 0] = w0;
    pair_w[2 * t + 1] = w1;

    int pos0 = atomicAdd(&count[i0], 1);
    bucket[i0 * T_TOK + pos0] = 2 * t + 0;
    int pos1 = atomicAdd(&count[i1], 1);
    bucket[i1 * T_TOK + pos1] = 2 * t + 1;
}

// ---------------------------------------------------------------
// Kernel 2: grouped GEMM1 + SiLU.
// act[pair, i] = silu(x[t]·w13[e,i,:]) * (x[t]·w13[e,I+i,:])
// Tile: 64 rows x 64 gate-cols (and the matching 64 up-cols), BK=16.
// 256 threads, 4x4 register blocking, two accumulators (gate, up).
// ---------------------------------------------------------------
__global__ __launch_bounds__(256) void gemm1_silu_kernel(
    const float* __restrict__ x, const float* __restrict__ w13,
    const int* __restrict__ count, const int* __restrict__ bucket,
    float* __restrict__ act)
{
    const int e   = blockIdx.z;
    const int n_e = count[e];
    const int m0  = blockIdx.y * 64;
    if (m0 >= n_e) return;
    const int n0  = blockIdx.x * 64;   // gate column base; up base = I_DIM + n0

    __shared__ float As[64][17];
    __shared__ float Bg[64][17];
    __shared__ float Bu[64][17];

    const int tid = threadIdx.x;
    const int lr  = tid >> 2;          // load row 0..63
    const int lc  = (tid & 3) * 4;     // load col 0,4,8,12

    // A row pointer (clamped for rows past n_e; stores are guarded)
    const int arow_idx = m0 + lr;
    const int pid_load = bucket[e * T_TOK + min(arow_idx, n_e - 1)];
    const float* xrow  = x + (size_t)(pid_load >> 1) * H_DIM;

    const float* gRow = w13 + ((size_t)e * 2048 + (n0 + lr)) * H_DIM;
    const float* uRow = w13 + ((size_t)e * 2048 + (I_DIM + n0 + lr)) * H_DIM;

    const int ty = tid >> 4;           // 0..15
    const int tx = tid & 15;           // 0..15

    float accg[4][4] = {{0.f}};
    float accu[4][4] = {{0.f}};

    for (int k0 = 0; k0 < H_DIM; k0 += 16) {
        float4 av = *(const float4*)(xrow + k0 + lc);
        float4 gv = *(const float4*)(gRow + k0 + lc);
        float4 uv = *(const float4*)(uRow + k0 + lc);
        __syncthreads();
        As[lr][lc+0] = av.x; As[lr][lc+1] = av.y; As[lr][lc+2] = av.z; As[lr][lc+3] = av.w;
        Bg[lr][lc+0] = gv.x; Bg[lr][lc+1] = gv.y; Bg[lr][lc+2] = gv.z; Bg[lr][lc+3] = gv.w;
        Bu[lr][lc+0] = uv.x; Bu[lr][lc+1] = uv.y; Bu[lr][lc+2] = uv.z; Bu[lr][lc+3] = uv.w;
        __syncthreads();
#pragma unroll
        for (int k = 0; k < 16; ++k) {
            float a[4], g[4], u[4];
#pragma unroll
            for (int m = 0; m < 4; ++m) a[m] = As[ty*4+m][k];
#pragma unroll
            for (int n = 0; n < 4; ++n) { g[n] = Bg[tx*4+n][k]; u[n] = Bu[tx*4+n][k]; }
#pragma unroll
            for (int m = 0; m < 4; ++m)
#pragma unroll
                for (int n = 0; n < 4; ++n) {
                    accg[m][n] = fmaf(a[m], g[n], accg[m][n]);
                    accu[m][n] = fmaf(a[m], u[n], accu[m][n]);
                }
        }
    }

#pragma unroll
    for (int m = 0; m < 4; ++m) {
        int r = m0 + ty * 4 + m;
        if (r < n_e) {
            int pid = bucket[e * T_TOK + r];
            float* arow = act + (size_t)pid * I_DIM + n0 + tx * 4;
#pragma unroll
            for (int n = 0; n < 4; ++n) {
                float g = accg[m][n];
                float u = accu[m][n];
                float sg = g / (1.f + expf(-g));   // silu
                arow[n] = sg * u;
            }
        }
    }
}

// ---------------------------------------------------------------
// Kernel 3: grouped GEMM2.
// y[pair, h] = act[pair,:]·w2[e,h,:]   (K = I_DIM = 1024)
// ---------------------------------------------------------------
__global__ __launch_bounds__(256) void gemm2_kernel(
    const float* __restrict__ act, const float* __restrict__ w2,
    const int* __restrict__ count, const int* __restrict__ bucket,
    float* __restrict__ y)
{
    const int e   = blockIdx.z;
    const int n_e = count[e];
    const int m0  = blockIdx.y * 64;
    if (m0 >= n_e) return;
    const int h0  = blockIdx.x * 64;

    __shared__ float As[64][17];
    __shared__ float Bs[64][17];

    const int tid = threadIdx.x;
    const int lr  = tid >> 2;
    const int lc  = (tid & 3) * 4;

    const int arow_idx = m0 + lr;
    const int pid_load = bucket[e * T_TOK + min(arow_idx, n_e - 1)];
    const float* arow  = act + (size_t)pid_load * I_DIM;
    const float* brow  = w2 + ((size_t)e * H_DIM + (h0 + lr)) * I_DIM;

    const int ty = tid >> 4;
    const int tx = tid & 15;

    float acc[4][4] = {{0.f}};

    for (int k0 = 0; k0 < I_DIM; k0 += 16) {
        float4 av = *(const float4*)(arow + k0 + lc);
        float4 bv = *(const float4*)(brow + k0 + lc);
        __syncthreads();
        As[lr][lc+0] = av.x; As[lr][lc+1] = av.y; As[lr][lc+2] = av.z; As[lr][lc+3] = av.w;
        Bs[lr][lc+0] = bv.x; Bs[lr][lc+1] = bv.y; Bs[lr][lc+2] = bv.z; Bs[lr][lc+3] = bv.w;
        __syncthreads();
#pragma unroll
        for (int k = 0; k < 16; ++k) {
            float a[4], b[4];
#pragma unroll
            for (int m = 0; m < 4; ++m) a[m] = As[ty*4+m][k];
#pragma unroll
            for (int n = 0; n < 4; ++n) b[n] = Bs[tx*4+n][k];
#pragma unroll
            for (int m = 0; m < 4; ++m)
#pragma unroll
                for (int n = 0; n < 4; ++n)
                    acc[m][n] = fmaf(a[m], b[n], acc[m][n]);
        }
    }

#pragma unroll
    for (int m = 0; m < 4; ++m) {
        int r = m0 + ty * 4 + m;
        if (r < n_e) {
            int pid = bucket[e * T_TOK + r];
            float* yrow = y + (size_t)pid * H_DIM + h0 + tx * 4;
#pragma unroll
            for (int n = 0; n < 4; ++n) yrow[n] = acc[m][n];
        }
    }
}

// ---------------------------------------------------------------
// Kernel 4: combine. out[t,h] = w0*y[2t,h] + w1*y[2t+1,h]
// ---------------------------------------------------------------
__global__ __launch_bounds__(256) void combine_kernel(
    const float* __restrict__ y, const float* __restrict__ pair_w,
    float* __restrict__ out)
{
    int idx = blockIdx.x * 256 + threadIdx.x;   // over 512*512 float4s
    int t = idx >> 9;
    int c = idx & 511;
    float w0 = pair_w[2 * t + 0];
    float w1 = pair_w[2 * t + 1];
    float4 y0 = ((const float4*)(y + (size_t)(2 * t + 0) * H_DIM))[c];
    float4 y1 = ((const float4*)(y + (size_t)(2 * t + 1) * H_DIM))[c];
    float4 o;
    o.x = w0 * y0.x + w1 * y1.x;
    o.y = w0 * y0.y + w1 * y1.y;
    o.z = w0 * y0.z + w1 * y1.z;
    o.w = w0 * y0.w + w1 * y1.w;
    ((float4*)(out + (size_t)t * H_DIM))[c] = o;
}

extern "C" void kernel_launch(void* const* d_in, const int* in_sizes, int n_in,
                              void* d_out, int out_size, void* d_ws, size_t ws_size,
                              hipStream_t stream) {
    const float* x      = (const float*)d_in[0];
    const float* logits = (const float*)d_in[1];
    const float* w13    = (const float*)d_in[2];
    const float* w2     = (const float*)d_in[3];
    float* out = (float*)d_out;

    int*   count  = (int*)d_ws;                    // 8
    int*   bucket = count + E_NUM;                 // 8*512
    float* pair_w = (float*)(bucket + E_NUM * T_TOK); // 1024
    float* act    = pair_w + 2 * T_TOK;            // 1024*1024
    float* ybuf   = act + (size_t)2 * T_TOK * I_DIM; // 1024*2048

    routing_kernel<<<1, 512, 0, stream>>>(logits, count, bucket, pair_w);
    gemm1_silu_kernel<<<dim3(I_DIM / 64, T_TOK / 64, E_NUM), 256, 0, stream>>>(
        x, w13, count, bucket, act);
    gemm2_kernel<<<dim3(H_DIM / 64, T_TOK / 64, E_NUM), 256, 0, stream>>>(
        act, w2, count, bucket, ybuf);
    combine_kernel<<<(T_TOK * (H_DIM / 4)) / 256, 256, 0, stream>>>(
        ybuf, pair_w, out);
}

// Round 2
// 151.554 us; speedup vs baseline: 4.3865x; 4.3865x over previous
//
#include <hip/hip_runtime.h>
#include <hip/hip_bf16.h>

#define T_TOK 512
#define H_DIM 2048
#define E_NUM 8
#define I_DIM 1024

typedef __attribute__((ext_vector_type(8))) short short8;
typedef __attribute__((ext_vector_type(4))) float f32x4;

// round-to-nearest-even float -> bf16 (as ushort)
__device__ __forceinline__ unsigned short f2bf(float f) {
    unsigned int u = __float_as_uint(f);
    u += 0x7fff + ((u >> 16) & 1);
    return (unsigned short)(u >> 16);
}

__device__ __forceinline__ short8 pack8(float4 a, float4 b) {
    short8 r;
    r[0] = (short)f2bf(a.x); r[1] = (short)f2bf(a.y);
    r[2] = (short)f2bf(a.z); r[3] = (short)f2bf(a.w);
    r[4] = (short)f2bf(b.x); r[5] = (short)f2bf(b.y);
    r[6] = (short)f2bf(b.z); r[7] = (short)f2bf(b.w);
    return r;
}

// ---------------------------------------------------------------
// Kernel 1: routing (unchanged). 1 block, 512 threads.
// ---------------------------------------------------------------
__global__ __launch_bounds__(512) void routing_kernel(
    const float* __restrict__ logits,
    int* __restrict__ count, int* __restrict__ bucket,
    float* __restrict__ pair_w)
{
    int t = threadIdx.x;
    if (t < E_NUM) count[t] = 0;
    __syncthreads();

    float p[E_NUM];
    float m = -INFINITY;
#pragma unroll
    for (int e = 0; e < E_NUM; ++e) {
        p[e] = logits[t * E_NUM + e];
        m = fmaxf(m, p[e]);
    }
#pragma unroll
    for (int e = 0; e < E_NUM; ++e) p[e] = expf(p[e] - m);
    int i0 = 0;
#pragma unroll
    for (int e = 1; e < E_NUM; ++e) if (p[e] > p[i0]) i0 = e;
    int i1 = (i0 == 0) ? 1 : 0;
#pragma unroll
    for (int e = 0; e < E_NUM; ++e) if (e != i0 && p[e] > p[i1]) i1 = e;
    float denom = p[i0] + p[i1];
    pair_w[2 * t + 0] = p[i0] / denom;
    pair_w[2 * t + 1] = p[i1] / denom;

    int pos0 = atomicAdd(&count[i0], 1);
    bucket[i0 * T_TOK + pos0] = 2 * t + 0;
    int pos1 = atomicAdd(&count[i1], 1);
    bucket[i1 * T_TOK + pos1] = 2 * t + 1;
}

// ---------------------------------------------------------------
// Kernel 2: grouped GEMM1 + SiLU (bf16 MFMA).
// Block: 256 thr = 4 waves. Tile 64 rows x (64 gate + 64 up cols), BK=64.
// Wave (wr,wc) computes rows wr*32..+32, cols wc*32..+32 (gate AND up).
// LDS tiles bf16 padded to stride 72 (144B rows: 16B-aligned, 2-way banks).
// act written as bf16.
// ---------------------------------------------------------------
__global__ __launch_bounds__(256) void gemm1_silu_kernel(
    const float* __restrict__ x, const float* __restrict__ w13,
    const int* __restrict__ count, const int* __restrict__ bucket,
    __hip_bfloat16* __restrict__ act)
{
    const int e   = blockIdx.z;
    const int n_e = count[e];
    const int m0  = blockIdx.y * 64;
    if (m0 >= n_e) return;
    const int n0  = blockIdx.x * 64;

    __shared__ unsigned short sA[64][72];
    __shared__ unsigned short sG[64][72];
    __shared__ unsigned short sU[64][72];

    const int tid = threadIdx.x;
    // staging coords: row 0..63, col quarter 0..3 (16 floats each)
    const int sr = tid >> 2;
    const int sc = (tid & 3) * 16;

    const int rowIdx   = m0 + sr;
    const int pid_load = bucket[e * T_TOK + min(rowIdx, n_e - 1)];
    const float* xrow  = x + (size_t)(pid_load >> 1) * H_DIM;
    const float* gRow  = w13 + ((size_t)e * (2 * I_DIM) + (n0 + sr)) * H_DIM;
    const float* uRow  = w13 + ((size_t)e * (2 * I_DIM) + (I_DIM + n0 + sr)) * H_DIM;

    // compute coords
    const int lane = tid & 63;
    const int wid  = tid >> 6;
    const int wr   = wid >> 1;   // 0..1 row-half
    const int wc   = wid & 1;    // 0..1 col-half
    const int fr   = lane & 15;
    const int fq   = lane >> 4;

    f32x4 accg[2][2] = {};
    f32x4 accu[2][2] = {};

    for (int kb = 0; kb < H_DIM; kb += 64) {
        float4 av0 = *(const float4*)(xrow + kb + sc);
        float4 av1 = *(const float4*)(xrow + kb + sc + 4);
        float4 av2 = *(const float4*)(xrow + kb + sc + 8);
        float4 av3 = *(const float4*)(xrow + kb + sc + 12);
        float4 gv0 = *(const float4*)(gRow + kb + sc);
        float4 gv1 = *(const float4*)(gRow + kb + sc + 4);
        float4 gv2 = *(const float4*)(gRow + kb + sc + 8);
        float4 gv3 = *(const float4*)(gRow + kb + sc + 12);
        float4 uv0 = *(const float4*)(uRow + kb + sc);
        float4 uv1 = *(const float4*)(uRow + kb + sc + 4);
        float4 uv2 = *(const float4*)(uRow + kb + sc + 8);
        float4 uv3 = *(const float4*)(uRow + kb + sc + 12);

        __syncthreads();   // previous iter's reads done
        *(short8*)&sA[sr][sc]     = pack8(av0, av1);
        *(short8*)&sA[sr][sc + 8] = pack8(av2, av3);
        *(short8*)&sG[sr][sc]     = pack8(gv0, gv1);
        *(short8*)&sG[sr][sc + 8] = pack8(gv2, gv3);
        *(short8*)&sU[sr][sc]     = pack8(uv0, uv1);
        *(short8*)&sU[sr][sc + 8] = pack8(uv2, uv3);
        __syncthreads();

#pragma unroll
        for (int kk = 0; kk < 2; ++kk) {
            short8 a[2], bg[2], bu[2];
#pragma unroll
            for (int m = 0; m < 2; ++m)
                a[m] = *(const short8*)&sA[wr * 32 + m * 16 + fr][kk * 32 + fq * 8];
#pragma unroll
            for (int n = 0; n < 2; ++n) {
                bg[n] = *(const short8*)&sG[wc * 32 + n * 16 + fr][kk * 32 + fq * 8];
                bu[n] = *(const short8*)&sU[wc * 32 + n * 16 + fr][kk * 32 + fq * 8];
            }
#pragma unroll
            for (int m = 0; m < 2; ++m)
#pragma unroll
                for (int n = 0; n < 2; ++n) {
                    accg[m][n] = __builtin_amdgcn_mfma_f32_16x16x32_bf16(a[m], bg[n], accg[m][n], 0, 0, 0);
                    accu[m][n] = __builtin_amdgcn_mfma_f32_16x16x32_bf16(a[m], bu[n], accu[m][n], 0, 0, 0);
                }
        }
    }

    // epilogue: silu(gate)*up -> act (bf16)
#pragma unroll
    for (int m = 0; m < 2; ++m) {
#pragma unroll
        for (int j = 0; j < 4; ++j) {
            int r = m0 + wr * 32 + m * 16 + fq * 4 + j;
            if (r < n_e) {
                int pid = bucket[e * T_TOK + r];
                __hip_bfloat16* arow = act + (size_t)pid * I_DIM;
#pragma unroll
                for (int n = 0; n < 2; ++n) {
                    float g = accg[m][n][j];
                    float u = accu[m][n][j];
                    float sg = g / (1.f + expf(-g));
                    unsigned short v = f2bf(sg * u);
                    int col = n0 + wc * 32 + n * 16 + fr;
                    *(unsigned short*)(arow + col) = v;
                }
            }
        }
    }
}

// ---------------------------------------------------------------
// Kernel 3: grouped GEMM2 (bf16 MFMA). y[pair,h] = act[pair,:]·w2[e,h,:]
// Tile 64x64, BK=64.
// ---------------------------------------------------------------
__global__ __launch_bounds__(256) void gemm2_kernel(
    const __hip_bfloat16* __restrict__ act, const float* __restrict__ w2,
    const int* __restrict__ count, const int* __restrict__ bucket,
    float* __restrict__ y)
{
    const int e   = blockIdx.z;
    const int n_e = count[e];
    const int m0  = blockIdx.y * 64;
    if (m0 >= n_e) return;
    const int h0  = blockIdx.x * 64;

    __shared__ unsigned short sA[64][72];
    __shared__ unsigned short sB[64][72];

    const int tid = threadIdx.x;
    const int sr = tid >> 2;
    const int sc = (tid & 3) * 16;

    const int rowIdx   = m0 + sr;
    const int pid_load = bucket[e * T_TOK + min(rowIdx, n_e - 1)];
    const __hip_bfloat16* arow = act + (size_t)pid_load * I_DIM;
    const float* brow = w2 + ((size_t)e * H_DIM + (h0 + sr)) * I_DIM;

    const int lane = tid & 63;
    const int wid  = tid >> 6;
    const int wr   = wid >> 1;
    const int wc   = wid & 1;
    const int fr   = lane & 15;
    const int fq   = lane >> 4;

    f32x4 acc[2][2] = {};

    for (int kb = 0; kb < I_DIM; kb += 64) {
        short8 aw0 = *(const short8*)(arow + kb + sc);
        short8 aw1 = *(const short8*)(arow + kb + sc + 8);
        float4 bv0 = *(const float4*)(brow + kb + sc);
        float4 bv1 = *(const float4*)(brow + kb + sc + 4);
        float4 bv2 = *(const float4*)(brow + kb + sc + 8);
        float4 bv3 = *(const float4*)(brow + kb + sc + 12);

        __syncthreads();
        *(short8*)&sA[sr][sc]     = aw0;
        *(short8*)&sA[sr][sc + 8] = aw1;
        *(short8*)&sB[sr][sc]     = pack8(bv0, bv1);
        *(short8*)&sB[sr][sc + 8] = pack8(bv2, bv3);
        __syncthreads();

#pragma unroll
        for (int kk = 0; kk < 2; ++kk) {
            short8 a[2], b[2];
#pragma unroll
            for (int m = 0; m < 2; ++m)
                a[m] = *(const short8*)&sA[wr * 32 + m * 16 + fr][kk * 32 + fq * 8];
#pragma unroll
            for (int n = 0; n < 2; ++n)
                b[n] = *(const short8*)&sB[wc * 32 + n * 16 + fr][kk * 32 + fq * 8];
#pragma unroll
            for (int m = 0; m < 2; ++m)
#pragma unroll
                for (int n = 0; n < 2; ++n)
                    acc[m][n] = __builtin_amdgcn_mfma_f32_16x16x32_bf16(a[m], b[n], acc[m][n], 0, 0, 0);
        }
    }

#pragma unroll
    for (int m = 0; m < 2; ++m) {
#pragma unroll
        for (int j = 0; j < 4; ++j) {
            int r = m0 + wr * 32 + m * 16 + fq * 4 + j;
            if (r < n_e) {
                int pid = bucket[e * T_TOK + r];
                float* yrow = y + (size_t)pid * H_DIM;
#pragma unroll
                for (int n = 0; n < 2; ++n)
                    yrow[h0 + wc * 32 + n * 16 + fr] = acc[m][n][j];
            }
        }
    }
}

// ---------------------------------------------------------------
// Kernel 4: combine. out[t,h] = w0*y[2t,h] + w1*y[2t+1,h]
// ---------------------------------------------------------------
__global__ __launch_bounds__(256) void combine_kernel(
    const float* __restrict__ y, const float* __restrict__ pair_w,
    float* __restrict__ out)
{
    int idx = blockIdx.x * 256 + threadIdx.x;
    int t = idx >> 9;
    int c = idx & 511;
    float w0 = pair_w[2 * t + 0];
    float w1 = pair_w[2 * t + 1];
    float4 y0 = ((const float4*)(y + (size_t)(2 * t + 0) * H_DIM))[c];
    float4 y1 = ((const float4*)(y + (size_t)(2 * t + 1) * H_DIM))[c];
    float4 o;
    o.x = w0 * y0.x + w1 * y1.x;
    o.y = w0 * y0.y + w1 * y1.y;
    o.z = w0 * y0.z + w1 * y1.z;
    o.w = w0 * y0.w + w1 * y1.w;
    ((float4*)(out + (size_t)t * H_DIM))[c] = o;
}

extern "C" void kernel_launch(void* const* d_in, const int* in_sizes, int n_in,
                              void* d_out, int out_size, void* d_ws, size_t ws_size,
                              hipStream_t stream) {
    const float* x      = (const float*)d_in[0];
    const float* logits = (const float*)d_in[1];
    const float* w13    = (const float*)d_in[2];
    const float* w2     = (const float*)d_in[3];
    float* out = (float*)d_out;

    int*   count  = (int*)d_ws;                         // 8
    int*   bucket = count + E_NUM;                      // 8*512
    float* pair_w = (float*)(bucket + E_NUM * T_TOK);   // 1024
    __hip_bfloat16* act = (__hip_bfloat16*)(pair_w + 2 * T_TOK);      // 1024*1024 bf16
    float* ybuf   = (float*)(act + (size_t)2 * T_TOK * I_DIM);        // 1024*2048 f32

    routing_kernel<<<1, 512, 0, stream>>>(logits, count, bucket, pair_w);
    gemm1_silu_kernel<<<dim3(I_DIM / 64, T_TOK / 64, E_NUM), 256, 0, stream>>>(
        x, w13, count, bucket, act);
    gemm2_kernel<<<dim3(H_DIM / 64, T_TOK / 64, E_NUM), 256, 0, stream>>>(
        act, w2, count, bucket, ybuf);
    combine_kernel<<<(T_TOK * (H_DIM / 4)) / 256, 256, 0, stream>>>(
        ybuf, pair_w, out);
}

// Round 3
// 100.295 us; speedup vs baseline: 6.6283x; 1.5111x over previous
//
#include <hip/hip_runtime.h>
#include <hip/hip_bf16.h>

#define T_TOK 512
#define H_DIM 2048
#define E_NUM 8
#define I_DIM 1024

typedef __attribute__((ext_vector_type(8))) short short8;
typedef __attribute__((ext_vector_type(4))) float f32x4;

// round-to-nearest-even float -> bf16 (as ushort)
__device__ __forceinline__ unsigned short f2bf(float f) {
    unsigned int u = __float_as_uint(f);
    u += 0x7fff + ((u >> 16) & 1);
    return (unsigned short)(u >> 16);
}

__device__ __forceinline__ short8 pack8(float4 a, float4 b) {
    short8 r;
    r[0] = (short)f2bf(a.x); r[1] = (short)f2bf(a.y);
    r[2] = (short)f2bf(a.z); r[3] = (short)f2bf(a.w);
    r[4] = (short)f2bf(b.x); r[5] = (short)f2bf(b.y);
    r[6] = (short)f2bf(b.z); r[7] = (short)f2bf(b.w);
    return r;
}

// 8 fp32 -> short8 of bf16 via packed cvt (RNE)
__device__ __forceinline__ short8 cvt8(float4 a, float4 b) {
    union { short8 s; __hip_bfloat162 h[4]; } u;
    u.h[0] = __float22bfloat162_rn(make_float2(a.x, a.y));
    u.h[1] = __float22bfloat162_rn(make_float2(a.z, a.w));
    u.h[2] = __float22bfloat162_rn(make_float2(b.x, b.y));
    u.h[3] = __float22bfloat162_rn(make_float2(b.z, b.w));
    return u.s;
}

// async global->LDS, 16B per lane; lds dest is wave-uniform base + lane*16
__device__ __forceinline__ void gload_lds16(const float* g, float* l) {
    __builtin_amdgcn_global_load_lds(
        (const __attribute__((address_space(1))) void*)g,
        (__attribute__((address_space(3))) void*)l, 16, 0, 0);
}

// ---------------------------------------------------------------
// Kernel 1: routing. 1 block, 512 threads.
// ---------------------------------------------------------------
__global__ __launch_bounds__(512) void routing_kernel(
    const float* __restrict__ logits,
    int* __restrict__ count, int* __restrict__ bucket,
    float* __restrict__ pair_w)
{
    int t = threadIdx.x;
    if (t < E_NUM) count[t] = 0;
    __syncthreads();

    float p[E_NUM];
    float m = -INFINITY;
#pragma unroll
    for (int e = 0; e < E_NUM; ++e) {
        p[e] = logits[t * E_NUM + e];
        m = fmaxf(m, p[e]);
    }
#pragma unroll
    for (int e = 0; e < E_NUM; ++e) p[e] = expf(p[e] - m);
    int i0 = 0;
#pragma unroll
    for (int e = 1; e < E_NUM; ++e) if (p[e] > p[i0]) i0 = e;
    int i1 = (i0 == 0) ? 1 : 0;
#pragma unroll
    for (int e = 0; e < E_NUM; ++e) if (e != i0 && p[e] > p[i1]) i1 = e;
    float denom = p[i0] + p[i1];
    pair_w[2 * t + 0] = p[i0] / denom;
    pair_w[2 * t + 1] = p[i1] / denom;

    int pos0 = atomicAdd(&count[i0], 1);
    bucket[i0 * T_TOK + pos0] = 2 * t + 0;
    int pos1 = atomicAdd(&count[i1], 1);
    bucket[i1 * T_TOK + pos1] = 2 * t + 1;
}

// ---------------------------------------------------------------
// Kernel 2: grouped GEMM1 + SiLU (bf16 MFMA).
// Staging: global_load_lds width-16, fp32 LDS tiles 64x64 (A, G, U),
// granule-level XOR swizzle (slot = granule ^ (row&7)) applied on the
// per-lane GLOBAL source (LDS dest linear) and inverted on LDS read.
// fp32->bf16 conversion at fragment-read time (cvt_pk).
// Loop: [barrier drain] frags -> [barrier] issue next stage -> MFMA.
// ---------------------------------------------------------------
__global__ __launch_bounds__(256) void gemm1_silu_kernel(
    const float* __restrict__ x, const float* __restrict__ w13,
    const int* __restrict__ count, const int* __restrict__ bucket,
    __hip_bfloat16* __restrict__ act)
{
    const int e   = blockIdx.z;
    const int n_e = count[e];
    const int m0  = blockIdx.y * 64;
    if (m0 >= n_e) return;
    const int n0  = blockIdx.x * 64;

    __shared__ float lds[3 * 64 * 64];   // 48 KB: sA, sG, sU  [64 rows][64 f32]
    float* sA = lds;
    float* sG = lds + 4096;
    float* sU = lds + 8192;

    const int tid  = threadIdx.x;
    const int lane = tid & 63;
    const int wid  = tid >> 6;     // 0..3
    const int fr   = lane & 15;
    const int fq   = lane >> 4;
    const int wr   = wid >> 1;
    const int wc   = wid & 1;

    // staging geometry: one instr = 64 lanes * 16B = 1KB = 4 rows of 64 f32.
    // wave wid stages rows [16*wid, 16*wid+16) of each tile = 4 instrs.
    const int lrow = lane >> 4;    // row within 4-row chunk
    const int slot = lane & 15;    // 16B granule slot within row

    const float* aptr[4];
    const float* gptr[4];
    const float* uptr[4];
#pragma unroll
    for (int i = 0; i < 4; ++i) {
        int r   = 16 * wid + 4 * i + lrow;        // LDS row 0..63
        int gsl = slot ^ (r & 7);                 // source granule (involution)
        int arow = min(m0 + r, n_e - 1);
        int tok  = bucket[e * T_TOK + arow] >> 1;
        aptr[i] = x + (size_t)tok * H_DIM + gsl * 4;
        gptr[i] = w13 + ((size_t)e * (2 * I_DIM) + n0 + r) * H_DIM + gsl * 4;
        uptr[i] = w13 + ((size_t)e * (2 * I_DIM) + I_DIM + n0 + r) * H_DIM + gsl * 4;
    }

    f32x4 accg[2][2] = {};
    f32x4 accu[2][2] = {};

    // prologue: stage K-tile 0
#pragma unroll
    for (int i = 0; i < 4; ++i) {
        float* dA = &sA[(16 * wid + 4 * i) * 64];
        float* dG = &sG[(16 * wid + 4 * i) * 64];
        float* dU = &sU[(16 * wid + 4 * i) * 64];
        gload_lds16(aptr[i], dA);
        gload_lds16(gptr[i], dG);
        gload_lds16(uptr[i], dU);
    }

    for (int kb = 64; kb <= H_DIM; kb += 64) {
        __syncthreads();   // drain current tile's DMA

        short8 a[2][2], bg[2][2], bu[2][2];
#pragma unroll
        for (int kk = 0; kk < 2; ++kk) {
#pragma unroll
            for (int m = 0; m < 2; ++m) {
                int r  = wr * 32 + m * 16 + fr;
                int s0 = (kk * 8 + fq * 2) ^ (r & 7);
                float4 q0 = *(const float4*)&sA[r * 64 + s0 * 4];
                float4 q1 = *(const float4*)&sA[r * 64 + (s0 ^ 1) * 4];
                a[kk][m] = cvt8(q0, q1);
            }
#pragma unroll
            for (int n = 0; n < 2; ++n) {
                int r  = wc * 32 + n * 16 + fr;
                int s0 = (kk * 8 + fq * 2) ^ (r & 7);
                float4 g0 = *(const float4*)&sG[r * 64 + s0 * 4];
                float4 g1 = *(const float4*)&sG[r * 64 + (s0 ^ 1) * 4];
                bg[kk][n] = cvt8(g0, g1);
                float4 u0 = *(const float4*)&sU[r * 64 + s0 * 4];
                float4 u1 = *(const float4*)&sU[r * 64 + (s0 ^ 1) * 4];
                bu[kk][n] = cvt8(u0, u1);
            }
        }
        __syncthreads();   // all waves done reading LDS

        if (kb < H_DIM) {  // issue next tile's DMA; MFMAs below overlap it
#pragma unroll
            for (int i = 0; i < 4; ++i) {
                float* dA = &sA[(16 * wid + 4 * i) * 64];
                float* dG = &sG[(16 * wid + 4 * i) * 64];
                float* dU = &sU[(16 * wid + 4 * i) * 64];
                gload_lds16(aptr[i] + kb, dA);
                gload_lds16(gptr[i] + kb, dG);
                gload_lds16(uptr[i] + kb, dU);
            }
        }

#pragma unroll
        for (int kk = 0; kk < 2; ++kk)
#pragma unroll
            for (int m = 0; m < 2; ++m)
#pragma unroll
                for (int n = 0; n < 2; ++n) {
                    accg[m][n] = __builtin_amdgcn_mfma_f32_16x16x32_bf16(a[kk][m], bg[kk][n], accg[m][n], 0, 0, 0);
                    accu[m][n] = __builtin_amdgcn_mfma_f32_16x16x32_bf16(a[kk][m], bu[kk][n], accu[m][n], 0, 0, 0);
                }
    }

    // epilogue: silu(gate)*up -> act (bf16)
#pragma unroll
    for (int m = 0; m < 2; ++m) {
#pragma unroll
        for (int j = 0; j < 4; ++j) {
            int r = m0 + wr * 32 + m * 16 + fq * 4 + j;
            if (r < n_e) {
                int pid = bucket[e * T_TOK + r];
                __hip_bfloat16* arow = act + (size_t)pid * I_DIM;
#pragma unroll
                for (int n = 0; n < 2; ++n) {
                    float g = accg[m][n][j];
                    float u = accu[m][n][j];
                    float sg = g / (1.f + expf(-g));
                    unsigned short v = f2bf(sg * u);
                    int col = n0 + wc * 32 + n * 16 + fr;
                    *(unsigned short*)(arow + col) = v;
                }
            }
        }
    }
}

// ---------------------------------------------------------------
// Kernel 3: grouped GEMM2 (bf16 MFMA). y[pair,h] = act[pair,:]·w2[e,h,:]
// ---------------------------------------------------------------
__global__ __launch_bounds__(256) void gemm2_kernel(
    const __hip_bfloat16* __restrict__ act, const float* __restrict__ w2,
    const int* __restrict__ count, const int* __restrict__ bucket,
    float* __restrict__ y)
{
    const int e   = blockIdx.z;
    const int n_e = count[e];
    const int m0  = blockIdx.y * 64;
    if (m0 >= n_e) return;
    const int h0  = blockIdx.x * 64;

    __shared__ unsigned short sA[64][72];
    __shared__ unsigned short sB[64][72];

    const int tid = threadIdx.x;
    const int sr = tid >> 2;
    const int sc = (tid & 3) * 16;

    const int rowIdx   = m0 + sr;
    const int pid_load = bucket[e * T_TOK + min(rowIdx, n_e - 1)];
    const __hip_bfloat16* arow = act + (size_t)pid_load * I_DIM;
    const float* brow = w2 + ((size_t)e * H_DIM + (h0 + sr)) * I_DIM;

    const int lane = tid & 63;
    const int wid  = tid >> 6;
    const int wr   = wid >> 1;
    const int wc   = wid & 1;
    const int fr   = lane & 15;
    const int fq   = lane >> 4;

    f32x4 acc[2][2] = {};

    for (int kb = 0; kb < I_DIM; kb += 64) {
        short8 aw0 = *(const short8*)(arow + kb + sc);
        short8 aw1 = *(const short8*)(arow + kb + sc + 8);
        float4 bv0 = *(const float4*)(brow + kb + sc);
        float4 bv1 = *(const float4*)(brow + kb + sc + 4);
        float4 bv2 = *(const float4*)(brow + kb + sc + 8);
        float4 bv3 = *(const float4*)(brow + kb + sc + 12);

        __syncthreads();
        *(short8*)&sA[sr][sc]     = aw0;
        *(short8*)&sA[sr][sc + 8] = aw1;
        *(short8*)&sB[sr][sc]     = pack8(bv0, bv1);
        *(short8*)&sB[sr][sc + 8] = pack8(bv2, bv3);
        __syncthreads();

#pragma unroll
        for (int kk = 0; kk < 2; ++kk) {
            short8 a[2], b[2];
#pragma unroll
            for (int m = 0; m < 2; ++m)
                a[m] = *(const short8*)&sA[wr * 32 + m * 16 + fr][kk * 32 + fq * 8];
#pragma unroll
            for (int n = 0; n < 2; ++n)
                b[n] = *(const short8*)&sB[wc * 32 + n * 16 + fr][kk * 32 + fq * 8];
#pragma unroll
            for (int m = 0; m < 2; ++m)
#pragma unroll
                for (int n = 0; n < 2; ++n)
                    acc[m][n] = __builtin_amdgcn_mfma_f32_16x16x32_bf16(a[m], b[n], acc[m][n], 0, 0, 0);
        }
    }

#pragma unroll
    for (int m = 0; m < 2; ++m) {
#pragma unroll
        for (int j = 0; j < 4; ++j) {
            int r = m0 + wr * 32 + m * 16 + fq * 4 + j;
            if (r < n_e) {
                int pid = bucket[e * T_TOK + r];
                float* yrow = y + (size_t)pid * H_DIM;
#pragma unroll
                for (int n = 0; n < 2; ++n)
                    yrow[h0 + wc * 32 + n * 16 + fr] = acc[m][n][j];
            }
        }
    }
}

// ---------------------------------------------------------------
// Kernel 4: combine. out[t,h] = w0*y[2t,h] + w1*y[2t+1,h]
// ---------------------------------------------------------------
__global__ __launch_bounds__(256) void combine_kernel(
    const float* __restrict__ y, const float* __restrict__ pair_w,
    float* __restrict__ out)
{
    int idx = blockIdx.x * 256 + threadIdx.x;
    int t = idx >> 9;
    int c = idx & 511;
    float w0 = pair_w[2 * t + 0];
    float w1 = pair_w[2 * t + 1];
    float4 y0 = ((const float4*)(y + (size_t)(2 * t + 0) * H_DIM))[c];
    float4 y1 = ((const float4*)(y + (size_t)(2 * t + 1) * H_DIM))[c];
    float4 o;
    o.x = w0 * y0.x + w1 * y1.x;
    o.y = w0 * y0.y + w1 * y1.y;
    o.z = w0 * y0.z + w1 * y1.z;
    o.w = w0 * y0.w + w1 * y1.w;
    ((float4*)(out + (size_t)t * H_DIM))[c] = o;
}

extern "C" void kernel_launch(void* const* d_in, const int* in_sizes, int n_in,
                              void* d_out, int out_size, void* d_ws, size_t ws_size,
                              hipStream_t stream) {
    const float* x      = (const float*)d_in[0];
    const float* logits = (const float*)d_in[1];
    const float* w13    = (const float*)d_in[2];
    const float* w2     = (const float*)d_in[3];
    float* out = (float*)d_out;

    int*   count  = (int*)d_ws;                         // 8
    int*   bucket = count + E_NUM;                      // 8*512
    float* pair_w = (float*)(bucket + E_NUM * T_TOK);   // 1024
    __hip_bfloat16* act = (__hip_bfloat16*)(pair_w + 2 * T_TOK);      // 1024*1024 bf16
    float* ybuf   = (float*)(act + (size_t)2 * T_TOK * I_DIM);        // 1024*2048 f32

    routing_kernel<<<1, 512, 0, stream>>>(logits, count, bucket, pair_w);
    gemm1_silu_kernel<<<dim3(I_DIM / 64, T_TOK / 64, E_NUM), 256, 0, stream>>>(
        x, w13, count, bucket, act);
    gemm2_kernel<<<dim3(H_DIM / 64, T_TOK / 64, E_NUM), 256, 0, stream>>>(
        act, w2, count, bucket, ybuf);
    combine_kernel<<<(T_TOK * (H_DIM / 4)) / 256, 256, 0, stream>>>(
        ybuf, pair_w, out);
}

// Round 4
// 95.783 us; speedup vs baseline: 6.9405x; 1.0471x over previous
//
#include <hip/hip_runtime.h>
#include <hip/hip_bf16.h>

#define T_TOK 512
#define H_DIM 2048
#define E_NUM 8
#define I_DIM 1024

typedef __attribute__((ext_vector_type(8))) short short8;
typedef __attribute__((ext_vector_type(4))) float f32x4;

// round-to-nearest-even float -> bf16 (as ushort)
__device__ __forceinline__ unsigned short f2bf(float f) {
    unsigned int u = __float_as_uint(f);
    u += 0x7fff + ((u >> 16) & 1);
    return (unsigned short)(u >> 16);
}

// 8 fp32 -> short8 of bf16 via packed cvt (RNE)
__device__ __forceinline__ short8 cvt8(float4 a, float4 b) {
    union { short8 s; __hip_bfloat162 h[4]; } u;
    u.h[0] = __float22bfloat162_rn(make_float2(a.x, a.y));
    u.h[1] = __float22bfloat162_rn(make_float2(a.z, a.w));
    u.h[2] = __float22bfloat162_rn(make_float2(b.x, b.y));
    u.h[3] = __float22bfloat162_rn(make_float2(b.z, b.w));
    return u.s;
}

// async global->LDS, 16B per lane; lds dest is wave-uniform base + lane*16
__device__ __forceinline__ void gload_lds16(const void* g, void* l) {
    __builtin_amdgcn_global_load_lds(
        (const __attribute__((address_space(1))) void*)g,
        (__attribute__((address_space(3))) void*)l, 16, 0, 0);
}

// ---------------------------------------------------------------
// Kernel 1: routing. 1 block, 512 threads.
// ---------------------------------------------------------------
__global__ __launch_bounds__(512) void routing_kernel(
    const float* __restrict__ logits,
    int* __restrict__ count, int* __restrict__ bucket,
    float* __restrict__ pair_w)
{
    int t = threadIdx.x;
    if (t < E_NUM) count[t] = 0;
    __syncthreads();

    float p[E_NUM];
    float m = -INFINITY;
#pragma unroll
    for (int e = 0; e < E_NUM; ++e) {
        p[e] = logits[t * E_NUM + e];
        m = fmaxf(m, p[e]);
    }
#pragma unroll
    for (int e = 0; e < E_NUM; ++e) p[e] = expf(p[e] - m);
    int i0 = 0;
#pragma unroll
    for (int e = 1; e < E_NUM; ++e) if (p[e] > p[i0]) i0 = e;
    int i1 = (i0 == 0) ? 1 : 0;
#pragma unroll
    for (int e = 0; e < E_NUM; ++e) if (e != i0 && p[e] > p[i1]) i1 = e;
    float denom = p[i0] + p[i1];
    pair_w[2 * t + 0] = p[i0] / denom;
    pair_w[2 * t + 1] = p[i1] / denom;

    int pos0 = atomicAdd(&count[i0], 1);
    bucket[i0 * T_TOK + pos0] = 2 * t + 0;
    int pos1 = atomicAdd(&count[i1], 1);
    bucket[i1 * T_TOK + pos1] = 2 * t + 1;
}

// ---------------------------------------------------------------
// Kernel 2: grouped GEMM1 + SiLU (bf16 MFMA).
// Double-buffered DMA pipeline, BK=32, counted vmcnt(6), 2 barriers/iter.
// LDS per buffer: A,G,U fp32 [64][32], granule-XOR swizzle (source-side
// inverse, read-side forward; LDS dest linear for global_load_lds).
// ---------------------------------------------------------------
__global__ __launch_bounds__(256) void gemm1_silu_kernel(
    const float* __restrict__ x, const float* __restrict__ w13,
    const int* __restrict__ count, const int* __restrict__ bucket,
    __hip_bfloat16* __restrict__ act)
{
    const int e   = blockIdx.z;
    const int n_e = count[e];
    const int m0  = blockIdx.y * 64;
    if (m0 >= n_e) return;
    const int n0  = blockIdx.x * 64;

    __shared__ float lds[2][3 * 64 * 32];   // 2 x 24 KB

    const int tid  = threadIdx.x;
    const int lane = tid & 63;
    const int wid  = tid >> 6;     // 0..3
    const int fr   = lane & 15;
    const int fq   = lane >> 4;
    const int wr   = wid >> 1;
    const int wc   = wid & 1;

    // staging: 1 DMA instr = 1 KB = 8 rows x 32 f32. Wave stages rows
    // [16*wid, 16*wid+16) of each tensor = 2 instrs/tensor.
    const int srow = lane >> 3;    // 0..7 within 8-row chunk
    const int slot = lane & 7;     // 16B granule within row

    const float *aptr[2], *gptr[2], *uptr[2];
#pragma unroll
    for (int ii = 0; ii < 2; ++ii) {
        int r   = 16 * wid + 8 * ii + srow;       // LDS row 0..63
        int gsl = slot ^ (r & 7);                 // pre-swizzled source granule
        int tok = bucket[e * T_TOK + min(m0 + r, n_e - 1)] >> 1;
        aptr[ii] = x + (size_t)tok * H_DIM + gsl * 4;
        gptr[ii] = w13 + ((size_t)e * (2 * I_DIM) + n0 + r) * H_DIM + gsl * 4;
        uptr[ii] = w13 + ((size_t)e * (2 * I_DIM) + I_DIM + n0 + r) * H_DIM + gsl * 4;
    }

    auto stage = [&](int kb, int buf) {
        float* b = lds[buf];
#pragma unroll
        for (int ii = 0; ii < 2; ++ii) {
            int rb = (16 * wid + 8 * ii) * 32;
            gload_lds16(aptr[ii] + kb, b + rb);
            gload_lds16(gptr[ii] + kb, b + 2048 + rb);
            gload_lds16(uptr[ii] + kb, b + 4096 + rb);
        }
    };

    f32x4 accg[2][2] = {};
    f32x4 accu[2][2] = {};
    short8 a[2], bg[2], bu[2];

    auto readfrags = [&](const float* b) {
#pragma unroll
        for (int m = 0; m < 2; ++m) {
            int r  = wr * 32 + m * 16 + fr;
            int s0 = (fq * 2) ^ (r & 7);
            float4 q0 = *(const float4*)(b + r * 32 + s0 * 4);
            float4 q1 = *(const float4*)(b + r * 32 + (s0 ^ 1) * 4);
            a[m] = cvt8(q0, q1);
        }
#pragma unroll
        for (int n = 0; n < 2; ++n) {
            int r  = wc * 32 + n * 16 + fr;
            int s0 = (fq * 2) ^ (r & 7);
            float4 g0 = *(const float4*)(b + 2048 + r * 32 + s0 * 4);
            float4 g1 = *(const float4*)(b + 2048 + r * 32 + (s0 ^ 1) * 4);
            bg[n] = cvt8(g0, g1);
            float4 u0 = *(const float4*)(b + 4096 + r * 32 + s0 * 4);
            float4 u1 = *(const float4*)(b + 4096 + r * 32 + (s0 ^ 1) * 4);
            bu[n] = cvt8(u0, u1);
        }
    };

    auto domfma = [&]() {
#pragma unroll
        for (int m = 0; m < 2; ++m)
#pragma unroll
            for (int n = 0; n < 2; ++n) {
                accg[m][n] = __builtin_amdgcn_mfma_f32_16x16x32_bf16(a[m], bg[n], accg[m][n], 0, 0, 0);
                accu[m][n] = __builtin_amdgcn_mfma_f32_16x16x32_bf16(a[m], bu[n], accu[m][n], 0, 0, 0);
            }
    };

    stage(0, 0);
#pragma unroll 2
    for (int t = 0; t < 63; ++t) {          // 64 K-tiles of 32
        stage((t + 1) * 32, (t + 1) & 1);   // issue next tile (other buffer)
        asm volatile("s_waitcnt vmcnt(6)" ::: "memory");   // own tile-t done
        __builtin_amdgcn_s_barrier();                      // all waves' tile-t done
        readfrags(lds[t & 1]);
        asm volatile("s_waitcnt lgkmcnt(0)" ::: "memory"); // reads complete
        __builtin_amdgcn_s_barrier();                      // buffer free for t+2
        domfma();
    }
    asm volatile("s_waitcnt vmcnt(0)" ::: "memory");
    __builtin_amdgcn_s_barrier();
    readfrags(lds[1]);
    domfma();

    // epilogue: silu(gate)*up -> act (bf16)
#pragma unroll
    for (int m = 0; m < 2; ++m) {
#pragma unroll
        for (int j = 0; j < 4; ++j) {
            int r = m0 + wr * 32 + m * 16 + fq * 4 + j;
            if (r < n_e) {
                int pid = bucket[e * T_TOK + r];
                __hip_bfloat16* arow = act + (size_t)pid * I_DIM;
#pragma unroll
                for (int n = 0; n < 2; ++n) {
                    float g = accg[m][n][j];
                    float u = accu[m][n][j];
                    float sg = g / (1.f + expf(-g));
                    unsigned short v = f2bf(sg * u);
                    int col = n0 + wc * 32 + n * 16 + fr;
                    *(unsigned short*)(arow + col) = v;
                }
            }
        }
    }
}

// ---------------------------------------------------------------
// Kernel 3: grouped GEMM2 (bf16 MFMA). Same pipeline, BK=64.
// A = act (bf16, direct frag reads), B = w2 (fp32, cvt at read).
// ---------------------------------------------------------------
__global__ __launch_bounds__(256) void gemm2_kernel(
    const __hip_bfloat16* __restrict__ act, const float* __restrict__ w2,
    const int* __restrict__ count, const int* __restrict__ bucket,
    float* __restrict__ y)
{
    const int e   = blockIdx.z;
    const int n_e = count[e];
    const int m0  = blockIdx.y * 64;
    if (m0 >= n_e) return;
    const int h0  = blockIdx.x * 64;

    __shared__ unsigned short sA[2][64 * 64];  // bf16 tile, 8 KB each
    __shared__ float sB[2][64 * 64];           // f32 tile, 16 KB each

    const int tid  = threadIdx.x;
    const int lane = tid & 63;
    const int wid  = tid >> 6;
    const int fr   = lane & 15;
    const int fq   = lane >> 4;
    const int wr   = wid >> 1;
    const int wc   = wid & 1;

    // A staging: 1 instr = 8 rows x 64 bf16 (128 B rows); 2 instrs/wave.
    const __hip_bfloat16* a2ptr[2];
#pragma unroll
    for (int ii = 0; ii < 2; ++ii) {
        int r   = 16 * wid + 8 * ii + (lane >> 3);
        int gsl = (lane & 7) ^ (r & 7);
        int pid = bucket[e * T_TOK + min(m0 + r, n_e - 1)];
        a2ptr[ii] = act + (size_t)pid * I_DIM + gsl * 8;
    }
    // B staging: 1 instr = 4 rows x 64 f32 (256 B rows); 4 instrs/wave.
    const float* b2ptr[4];
#pragma unroll
    for (int i = 0; i < 4; ++i) {
        int r   = 16 * wid + 4 * i + (lane >> 4);
        int gsl = (lane & 15) ^ (r & 7);
        b2ptr[i] = w2 + ((size_t)e * H_DIM + h0 + r) * I_DIM + gsl * 4;
    }

    auto stage = [&](int kb, int buf) {
#pragma unroll
        for (int ii = 0; ii < 2; ++ii)
            gload_lds16(a2ptr[ii] + kb, &sA[buf][(16 * wid + 8 * ii) * 64]);
#pragma unroll
        for (int i = 0; i < 4; ++i)
            gload_lds16(b2ptr[i] + kb, &sB[buf][(16 * wid + 4 * i) * 64]);
    };

    f32x4 acc[2][2] = {};
    short8 a[2][2], bf[2][2];

    auto readfrags = [&](int buf) {
#pragma unroll
        for (int kk = 0; kk < 2; ++kk) {
#pragma unroll
            for (int m = 0; m < 2; ++m) {
                int r = wr * 32 + m * 16 + fr;
                int g = (kk * 4 + fq) ^ (r & 7);
                a[kk][m] = *(const short8*)&sA[buf][r * 64 + g * 8];
            }
#pragma unroll
            for (int n = 0; n < 2; ++n) {
                int r  = wc * 32 + n * 16 + fr;
                int s0 = (kk * 8 + fq * 2) ^ (r & 7);
                float4 g0 = *(const float4*)&sB[buf][r * 64 + s0 * 4];
                float4 g1 = *(const float4*)&sB[buf][r * 64 + (s0 ^ 1) * 4];
                bf[kk][n] = cvt8(g0, g1);
            }
        }
    };

    auto domfma = [&]() {
#pragma unroll
        for (int kk = 0; kk < 2; ++kk)
#pragma unroll
            for (int m = 0; m < 2; ++m)
#pragma unroll
                for (int n = 0; n < 2; ++n)
                    acc[m][n] = __builtin_amdgcn_mfma_f32_16x16x32_bf16(a[kk][m], bf[kk][n], acc[m][n], 0, 0, 0);
    };

    stage(0, 0);
#pragma unroll 2
    for (int t = 0; t < 15; ++t) {          // 16 K-tiles of 64
        stage((t + 1) * 64, (t + 1) & 1);
        asm volatile("s_waitcnt vmcnt(6)" ::: "memory");
        __builtin_amdgcn_s_barrier();
        readfrags(t & 1);
        asm volatile("s_waitcnt lgkmcnt(0)" ::: "memory");
        __builtin_amdgcn_s_barrier();
        domfma();
    }
    asm volatile("s_waitcnt vmcnt(0)" ::: "memory");
    __builtin_amdgcn_s_barrier();
    readfrags(1);
    domfma();

#pragma unroll
    for (int m = 0; m < 2; ++m) {
#pragma unroll
        for (int j = 0; j < 4; ++j) {
            int r = m0 + wr * 32 + m * 16 + fq * 4 + j;
            if (r < n_e) {
                int pid = bucket[e * T_TOK + r];
                float* yrow = y + (size_t)pid * H_DIM;
#pragma unroll
                for (int n = 0; n < 2; ++n)
                    yrow[h0 + wc * 32 + n * 16 + fr] = acc[m][n][j];
            }
        }
    }
}

// ---------------------------------------------------------------
// Kernel 4: combine. out[t,h] = w0*y[2t,h] + w1*y[2t+1,h]
// ---------------------------------------------------------------
__global__ __launch_bounds__(256) void combine_kernel(
    const float* __restrict__ y, const float* __restrict__ pair_w,
    float* __restrict__ out)
{
    int idx = blockIdx.x * 256 + threadIdx.x;
    int t = idx >> 9;
    int c = idx & 511;
    float w0 = pair_w[2 * t + 0];
    float w1 = pair_w[2 * t + 1];
    float4 y0 = ((const float4*)(y + (size_t)(2 * t + 0) * H_DIM))[c];
    float4 y1 = ((const float4*)(y + (size_t)(2 * t + 1) * H_DIM))[c];
    float4 o;
    o.x = w0 * y0.x + w1 * y1.x;
    o.y = w0 * y0.y + w1 * y1.y;
    o.z = w0 * y0.z + w1 * y1.z;
    o.w = w0 * y0.w + w1 * y1.w;
    ((float4*)(out + (size_t)t * H_DIM))[c] = o;
}

extern "C" void kernel_launch(void* const* d_in, const int* in_sizes, int n_in,
                              void* d_out, int out_size, void* d_ws, size_t ws_size,
                              hipStream_t stream) {
    const float* x      = (const float*)d_in[0];
    const float* logits = (const float*)d_in[1];
    const float* w13    = (const float*)d_in[2];
    const float* w2     = (const float*)d_in[3];
    float* out = (float*)d_out;

    int*   count  = (int*)d_ws;                         // 8
    int*   bucket = count + E_NUM;                      // 8*512
    float* pair_w = (float*)(bucket + E_NUM * T_TOK);   // 1024
    __hip_bfloat16* act = (__hip_bfloat16*)(pair_w + 2 * T_TOK);      // 1024*1024 bf16
    float* ybuf   = (float*)(act + (size_t)2 * T_TOK * I_DIM);        // 1024*2048 f32

    routing_kernel<<<1, 512, 0, stream>>>(logits, count, bucket, pair_w);
    gemm1_silu_kernel<<<dim3(I_DIM / 64, T_TOK / 64, E_NUM), 256, 0, stream>>>(
        x, w13, count, bucket, act);
    gemm2_kernel<<<dim3(H_DIM / 64, T_TOK / 64, E_NUM), 256, 0, stream>>>(
        act, w2, count, bucket, ybuf);
    combine_kernel<<<(T_TOK * (H_DIM / 4)) / 256, 256, 0, stream>>>(
        ybuf, pair_w, out);
}